// Round 14
// baseline (313.566 us; speedup 1.0000x reference)
//
#include <hip/hip_runtime.h>
#include <hip/hip_fp16.h>

// B=8192, T=512, IN=1, H=20, OUT=1
#define B_TOTAL 8192
#define T_LEN   512
#define H       20
#define XSTR    524          // xs row stride (floats): (12b+t)%32 -> worst 2-way (free)
#define WROW    16           // packed weight row stride in dwords (64B)
// wpk layout (same as R13, HW-validated): matrix m {0:whh0,1:wih1,2:whh1,3:wih2,
// 4:whh2}, 32 rows each (rows 20..31 zero), row r: dwords 0..9 = f16 pairs of
// W[r][0..19], 10..15 = 0. A-frag lane(b,g): row b (or 16+b), dwords 4g..4g+3.

typedef _Float16 f16x8 __attribute__((ext_vector_type(8)));
typedef float    f32x4 __attribute__((ext_vector_type(4)));
typedef unsigned int u32;

#define MFMA(a, bf, c) __builtin_amdgcn_mfma_f32_16x16x32_f16((a), (bf), (c), 0, 0, 0)

__device__ __forceinline__ float fast_tanh(float x) {
    float e = __builtin_amdgcn_exp2f(x * 2.885390081777927f);
    return fmaf(-2.0f, __builtin_amdgcn_rcpf(e + 1.0f), 1.0f);
}

__device__ __forceinline__ u32 pk2(float a, float b) {
    return __builtin_bit_cast(u32, __builtin_amdgcn_cvt_pkrtz(a, b));
}

// D-layout -> B-fragment transform, fully in-register via ds_bpermute.
// d: rows j=4g+r (col=b). dh: rows j=16+r, valid on g==0 lanes.
// Result lane(b,g) = packed h[k=8g..8g+7] for batch b (zeros for k>=20).
__device__ __forceinline__ f16x8 xform(f32x4 d, f32x4 dh, int b, int g) {
    u32 p0  = pk2(fast_tanh(d[0]),  fast_tanh(d[1]));
    u32 p1  = pk2(fast_tanh(d[2]),  fast_tanh(d[3]));
    u32 ph0 = pk2(fast_tanh(dh[0]), fast_tanh(dh[1]));
    u32 ph1 = pk2(fast_tanh(dh[2]), fast_tanh(dh[3]));
    const int gl = g & 1;
    const int a0 = (b + 32 * gl) * 4;        // src lane (b, 2g)   [g<2]
    const int a1 = (b + 16 + 32 * gl) * 4;   // src lane (b, 2g+1) [g<2]
    u32 r0 = (u32)__builtin_amdgcn_ds_bpermute(a0, (int)p0);
    u32 r1 = (u32)__builtin_amdgcn_ds_bpermute(a0, (int)p1);
    u32 r2 = (u32)__builtin_amdgcn_ds_bpermute(a1, (int)p0);
    u32 r3 = (u32)__builtin_amdgcn_ds_bpermute(a1, (int)p1);
    u32 s0 = (u32)__builtin_amdgcn_ds_bpermute(b * 4, (int)ph0);  // j16,17 from (b,0)
    u32 s1 = (u32)__builtin_amdgcn_ds_bpermute(b * 4, (int)ph1);  // j18,19 from (b,0)
    uint4 dw;
    dw.x = g < 2 ? r0 : (g == 2 ? s0 : 0u);
    dw.y = g < 2 ? r1 : (g == 2 ? s1 : 0u);
    dw.z = g < 2 ? r2 : 0u;
    dw.w = g < 2 ? r3 : 0u;
    return __builtin_bit_cast(f16x8, dw);
}

// One tick: h0(s)[DO0], h1(s-1)[DO1], h2(s-2)[DO2]. All reads are prev-tick
// register values; single wave, no barriers anywhere.
#define TICK(sidx, DO0, DO1, DO2) { \
    f16x8 n0 = h0B, n1 = h1B, n2 = h2B; \
    if (DO0) { \
        float xv = xs[b][(sidx)]; \
        f32x4 c, ch; \
        c[0]=fmaf(xv,w0d[0],bd0[0]); c[1]=fmaf(xv,w0d[1],bd0[1]); \
        c[2]=fmaf(xv,w0d[2],bd0[2]); c[3]=fmaf(xv,w0d[3],bd0[3]); \
        ch[0]=fmaf(xv,w0h[0],bdh0[0]); ch[1]=fmaf(xv,w0h[1],bdh0[1]); \
        ch[2]=fmaf(xv,w0h[2],bdh0[2]); ch[3]=fmaf(xv,w0h[3],bdh0[3]); \
        f32x4 dd = MFMA(F0lo, h0B, c); \
        f32x4 dh = MFMA(F0hi, h0B, ch); \
        n0 = xform(dd, dh, b, g); \
    } \
    if (DO1) { \
        f32x4 dd = MFMA(F1lo, h0B, bd1);  dd = MFMA(F2lo, h1B, dd); \
        f32x4 dh = MFMA(F1hi, h0B, bdh1); dh = MFMA(F2hi, h1B, dh); \
        n1 = xform(dd, dh, b, g); \
    } \
    if (DO2) { \
        f32x4 dd = MFMA(F3lo, h1B, bd2);  dd = MFMA(F4lo, h2B, dd); \
        f32x4 dh = MFMA(F3hi, h1B, bdh2); dh = MFMA(F4hi, h2B, dh); \
        n2 = xform(dd, dh, b, g); \
    } \
    if (DO0) h0B = n0; \
    if (DO1) h1B = n1; \
    if (DO2) h2B = n2; \
}

// ---- prologue: pack 5 HxH f32 matrices into padded f16-pair rows (R13) ----
__global__ void prep_w(const float* __restrict__ w_hh0, const float* __restrict__ w_ih1,
                       const float* __restrict__ w_hh1, const float* __restrict__ w_ih2,
                       const float* __restrict__ w_hh2, unsigned int* __restrict__ ws)
{
    int i = threadIdx.x;                 // 256 threads, first 160 = (m, r)
    if (i < 160) {
        int m = i >> 5, r = i & 31;
        const float* src = (m == 0) ? w_hh0 : (m == 1) ? w_ih1 :
                           (m == 2) ? w_hh1 : (m == 3) ? w_ih2 : w_hh2;
        unsigned int* dst = ws + (m * 32 + r) * WROW;
        #pragma unroll
        for (int q = 0; q < 10; ++q) {
            unsigned int v = 0;
            if (r < H) {
                _Float16 lo = (_Float16)src[r * H + 2 * q];
                _Float16 hi = (_Float16)src[r * H + 2 * q + 1];
                v = (unsigned int)__builtin_bit_cast(unsigned short, lo)
                  | ((unsigned int)__builtin_bit_cast(unsigned short, hi) << 16);
            }
            dst[q] = v;
        }
        #pragma unroll
        for (int q = 10; q < 16; ++q) dst[q] = 0;
    }
}

// One wave per block, 16 batches, all 3 layers; zero barriers.
__global__ __launch_bounds__(64, 1) void rnn_mfma(
    const float* __restrict__ x,
    const float* __restrict__ w_ih0,
    const float* __restrict__ b_ih0, const float* __restrict__ b_hh0,
    const float* __restrict__ b_ih1, const float* __restrict__ b_hh1,
    const float* __restrict__ b_ih2, const float* __restrict__ b_hh2,
    const float* __restrict__ fc_w,  const float* __restrict__ fc_b,
    const unsigned int* __restrict__ wpk,
    float* __restrict__ out)
{
    __shared__ __align__(16) float xs[16][XSTR];

    const int l   = threadIdx.x;
    const int b   = l & 15;
    const int g   = l >> 4;
    const int gb0 = blockIdx.x * 16;

    // ---- stage x (coalesced float4); same-wave consumers -> no barrier ----
    for (int i = l; i < 16 * 128; i += 64) {
        int row = i >> 7, col = (i & 127) * 4;
        *(float4*)&xs[row][col] = *(const float4*)(x + (size_t)(gb0 + row) * T_LEN + col);
    }

    // ---- 10 weight A-fragments (40 VGPR) ----
    const f16x8* wp = (const f16x8*)wpk;
    const f16x8 F0lo = wp[(0 * 32 +      b) * 4 + g];
    const f16x8 F0hi = wp[(0 * 32 + 16 + b) * 4 + g];
    const f16x8 F1lo = wp[(1 * 32 +      b) * 4 + g];
    const f16x8 F1hi = wp[(1 * 32 + 16 + b) * 4 + g];
    const f16x8 F2lo = wp[(2 * 32 +      b) * 4 + g];
    const f16x8 F2hi = wp[(2 * 32 + 16 + b) * 4 + g];
    const f16x8 F3lo = wp[(3 * 32 +      b) * 4 + g];
    const f16x8 F3hi = wp[(3 * 32 + 16 + b) * 4 + g];
    const f16x8 F4lo = wp[(4 * 32 +      b) * 4 + g];
    const f16x8 F4hi = wp[(4 * 32 + 16 + b) * 4 + g];

    // ---- biases (D layout) + w_ih0 column ----
    f32x4 bd0, bdh0, bd1, bdh1, bd2, bdh2, w0d, w0h;
    #pragma unroll
    for (int r = 0; r < 4; ++r) {
        int j = 4 * g + r;
        bd0[r]  = b_ih0[j] + b_hh0[j];   bdh0[r] = b_ih0[16 + r] + b_hh0[16 + r];
        bd1[r]  = b_ih1[j] + b_hh1[j];   bdh1[r] = b_ih1[16 + r] + b_hh1[16 + r];
        bd2[r]  = b_ih2[j] + b_hh2[j];   bdh2[r] = b_ih2[16 + r] + b_hh2[16 + r];
        w0d[r]  = w_ih0[j];              w0h[r]  = w_ih0[16 + r];
    }

    // ---- h state fully in registers (B-fragment layout), init 0 ----
    uint4 z; z.x = 0u; z.y = 0u; z.z = 0u; z.w = 0u;
    f16x8 h0B = __builtin_bit_cast(f16x8, z);
    f16x8 h1B = h0B, h2B = h0B;

    // ---- diagonal pipeline, zero barriers ----
    TICK(0, 1, 0, 0)
    TICK(1, 1, 1, 0)
    for (int s = 2; s < T_LEN; ++s) {
        TICK(s, 1, 1, 1)
    }
    TICK(0, 0, 1, 1)   // h1(511), h2(510)
    TICK(0, 0, 0, 1)   // h2(511)

    // ---- FC epilogue: h2B = h2(511), k-slices per lane; reduce over g ----
    float acc = 0.f;
    #pragma unroll
    for (int i = 0; i < 8; ++i) {
        int k = 8 * g + i;
        if (k < H) acc = fmaf((float)h2B[i], fc_w[k], acc);
    }
    acc += __shfl_xor(acc, 16);
    acc += __shfl_xor(acc, 32);
    if (l < 16) out[gb0 + l] = acc + fc_b[0];
}

extern "C" void kernel_launch(void* const* d_in, const int* in_sizes, int n_in,
                              void* d_out, int out_size, void* d_ws, size_t ws_size,
                              hipStream_t stream) {
    const float* x     = (const float*)d_in[0];
    const float* w_ih0 = (const float*)d_in[1];
    const float* w_hh0 = (const float*)d_in[2];
    const float* b_ih0 = (const float*)d_in[3];
    const float* b_hh0 = (const float*)d_in[4];
    const float* w_ih1 = (const float*)d_in[5];
    const float* w_hh1 = (const float*)d_in[6];
    const float* b_ih1 = (const float*)d_in[7];
    const float* b_hh1 = (const float*)d_in[8];
    const float* w_ih2 = (const float*)d_in[9];
    const float* w_hh2 = (const float*)d_in[10];
    const float* b_ih2 = (const float*)d_in[11];
    const float* b_hh2 = (const float*)d_in[12];
    const float* fc_w  = (const float*)d_in[13];
    const float* fc_b  = (const float*)d_in[14];
    float* out = (float*)d_out;
    unsigned int* wpk = (unsigned int*)d_ws;   // 5 * 32 * 16 * 4 = 10240 B

    prep_w<<<1, 256, 0, stream>>>(w_hh0, w_ih1, w_hh1, w_ih2, w_hh2, wpk);

    rnn_mfma<<<B_TOTAL / 16, 64, 0, stream>>>(
        x, w_ih0, b_ih0, b_hh0, b_ih1, b_hh1, b_ih2, b_hh2,
        fc_w, fc_b, wpk, out);
}

// Round 15
// 186.478 us; speedup vs baseline: 1.6815x; 1.6815x over previous
//
#include <hip/hip_runtime.h>
#include <hip/hip_fp16.h>

// B=8192, T=512, IN=1, H=20, OUT=1
#define B_TOTAL 8192
#define T_LEN   512
#define H       20
#define XSTR    516          // xs row stride (floats): 516%32=4 -> 2-way max (free)
#define WROW    16           // packed weight row stride in dwords (64B)
#define KSTEP   4            // timesteps per barrier (super-tick)
// wpk layout (R13-validated): matrix m {0:whh0,1:wih1,2:whh1,3:wih2,4:whh2},
// 32 rows each (rows 20..31 zero), row r: dwords 0..9 = f16 pairs of W[r][0..19].
// A-frag lane(b,g): row b (or 16+b), dwords 4g..4g+3.

typedef _Float16 f16x8 __attribute__((ext_vector_type(8)));
typedef float    f32x4 __attribute__((ext_vector_type(4)));
typedef unsigned int u32;

#define MFMA(a, bf, c) __builtin_amdgcn_mfma_f32_16x16x32_f16((a), (bf), (c), 0, 0, 0)

__device__ __forceinline__ float fast_tanh(float x) {
    float e = __builtin_amdgcn_exp2f(x * 2.885390081777927f);
    return fmaf(-2.0f, __builtin_amdgcn_rcpf(e + 1.0f), 1.0f);
}

__device__ __forceinline__ u32 pk2(float a, float b) {
    return __builtin_bit_cast(u32, __builtin_amdgcn_cvt_pkrtz(a, b));
}

// D-layout -> B-fragment transform, in-register via ds_bpermute (R14-validated).
__device__ __forceinline__ f16x8 xform(f32x4 d, f32x4 dh, int b, int g) {
    u32 p0  = pk2(fast_tanh(d[0]),  fast_tanh(d[1]));
    u32 p1  = pk2(fast_tanh(d[2]),  fast_tanh(d[3]));
    u32 ph0 = pk2(fast_tanh(dh[0]), fast_tanh(dh[1]));
    u32 ph1 = pk2(fast_tanh(dh[2]), fast_tanh(dh[3]));
    const int gl = g & 1;
    const int a0 = (b + 32 * gl) * 4;        // src lane (b, 2g)   [g<2]
    const int a1 = (b + 16 + 32 * gl) * 4;   // src lane (b, 2g+1) [g<2]
    u32 r0 = (u32)__builtin_amdgcn_ds_bpermute(a0, (int)p0);
    u32 r1 = (u32)__builtin_amdgcn_ds_bpermute(a0, (int)p1);
    u32 r2 = (u32)__builtin_amdgcn_ds_bpermute(a1, (int)p0);
    u32 r3 = (u32)__builtin_amdgcn_ds_bpermute(a1, (int)p1);
    u32 s0 = (u32)__builtin_amdgcn_ds_bpermute(b * 4, (int)ph0);
    u32 s1 = (u32)__builtin_amdgcn_ds_bpermute(b * 4, (int)ph1);
    uint4 dw;
    dw.x = g < 2 ? r0 : (g == 2 ? s0 : 0u);
    dw.y = g < 2 ? r1 : (g == 2 ? s1 : 0u);
    dw.z = g < 2 ? r2 : 0u;
    dw.w = g < 2 ? r3 : 0u;
    return __builtin_bit_cast(f16x8, dw);
}

// ---- prologue: pack 5 HxH f32 matrices into padded f16-pair rows (R13) ----
__global__ void prep_w(const float* __restrict__ w_hh0, const float* __restrict__ w_ih1,
                       const float* __restrict__ w_hh1, const float* __restrict__ w_ih2,
                       const float* __restrict__ w_hh2, unsigned int* __restrict__ ws)
{
    int i = threadIdx.x;                 // 256 threads, first 160 = (m, r)
    if (i < 160) {
        int m = i >> 5, r = i & 31;
        const float* src = (m == 0) ? w_hh0 : (m == 1) ? w_ih1 :
                           (m == 2) ? w_hh1 : (m == 3) ? w_ih2 : w_hh2;
        unsigned int* dst = ws + (m * 32 + r) * WROW;
        #pragma unroll
        for (int q = 0; q < 10; ++q) {
            unsigned int v = 0;
            if (r < H) {
                _Float16 lo = (_Float16)src[r * H + 2 * q];
                _Float16 hi = (_Float16)src[r * H + 2 * q + 1];
                v = (unsigned int)__builtin_bit_cast(unsigned short, lo)
                  | ((unsigned int)__builtin_bit_cast(unsigned short, hi) << 16);
            }
            dst[q] = v;
        }
        #pragma unroll
        for (int q = 10; q < 16; ++q) dst[q] = 0;
    }
}

// 3 waves/block (one layer each), 16 batches/block, KSTEP=4 timesteps per
// barrier. Own-layer state in registers (xform); cross-layer handoff = one
// b128 LDS write/read per step, prefetched 4-at-once.
__global__ __launch_bounds__(192, 2) void rnn_mfma(
    const float* __restrict__ x,
    const float* __restrict__ w_ih0,
    const float* __restrict__ b_ih0, const float* __restrict__ b_hh0,
    const float* __restrict__ b_ih1, const float* __restrict__ b_hh1,
    const float* __restrict__ b_ih2, const float* __restrict__ b_hh2,
    const float* __restrict__ fc_w,  const float* __restrict__ fc_b,
    const unsigned int* __restrict__ wpk,
    float* __restrict__ out)
{
    __shared__ __align__(16) float xs[16][XSTR];
    __shared__ __align__(16) uint4 h0b[2][KSTEP][16][4];   // wv0 -> wv1
    __shared__ __align__(16) uint4 h1b[2][KSTEP][16][4];   // wv1 -> wv2

    const int tid = threadIdx.x;
    const int wv  = tid >> 6;
    const int l   = tid & 63;
    const int b   = l & 15;
    const int g   = l >> 4;
    const int gb0 = blockIdx.x * 16;

    // ---- stage x (coalesced float4) ----
    for (int i = tid; i < 16 * 128; i += 192) {
        int row = i >> 7, col = (i & 127) * 4;
        *(float4*)&xs[row][col] = *(const float4*)(x + (size_t)(gb0 + row) * T_LEN + col);
    }

    // ---- per-wave weight A-fragments ----
    const int mA = (wv == 0) ? 0 : (wv == 1) ? 1 : 3;
    const int mB = (wv == 0) ? 0 : (wv == 1) ? 2 : 4;
    const f16x8* wp = (const f16x8*)wpk;
    const f16x8 FaLo = wp[(mA * 32 +      b) * 4 + g];
    const f16x8 FaHi = wp[(mA * 32 + 16 + b) * 4 + g];
    const f16x8 FbLo = wp[(mB * 32 +      b) * 4 + g];
    const f16x8 FbHi = wp[(mB * 32 + 16 + b) * 4 + g];

    // ---- per-wave biases (D layout) + w_ih0 column for wave 0 ----
    const float* bi = (wv == 0) ? b_ih0 : (wv == 1) ? b_ih1 : b_ih2;
    const float* bh = (wv == 0) ? b_hh0 : (wv == 1) ? b_hh1 : b_hh2;
    f32x4 bd, bdh, w0d, w0h;
    #pragma unroll
    for (int r = 0; r < 4; ++r) {
        int j = 4 * g + r;
        bd[r]  = bi[j] + bh[j];
        bdh[r] = bi[16 + r] + bh[16 + r];
        w0d[r] = w_ih0[j];
        w0h[r] = w_ih0[16 + r];
    }

    // ---- own-layer recurrent state, B-fragment layout, in registers ----
    uint4 z; z.x = 0u; z.y = 0u; z.z = 0u; z.w = 0u;
    f16x8 hB = __builtin_bit_cast(f16x8, z);

    const int NSUP = T_LEN / KSTEP + 2;   // 130 super-ticks

    for (int m = 0; m < NSUP; ++m) {
        __syncthreads();
        if (wv == 0) {
            if (m < T_LEN / KSTEP) {
                float xv[KSTEP];
                #pragma unroll
                for (int s = 0; s < KSTEP; ++s) xv[s] = xs[b][KSTEP * m + s];
                #pragma unroll
                for (int s = 0; s < KSTEP; ++s) {
                    f32x4 c, ch;
                    #pragma unroll
                    for (int r = 0; r < 4; ++r) {
                        c[r]  = fmaf(xv[s], w0d[r], bd[r]);
                        ch[r] = fmaf(xv[s], w0h[r], bdh[r]);
                    }
                    f32x4 dd = MFMA(FaLo, hB, c);
                    f32x4 dh = MFMA(FaHi, hB, ch);
                    hB = xform(dd, dh, b, g);
                    h0b[m & 1][s][b][g] = __builtin_bit_cast(uint4, hB);
                }
            }
        } else if (wv == 1) {
            if (m >= 1 && m <= T_LEN / KSTEP) {
                f16x8 B0[KSTEP];
                #pragma unroll
                for (int s = 0; s < KSTEP; ++s)
                    B0[s] = __builtin_bit_cast(f16x8, h0b[(m - 1) & 1][s][b][g]);
                #pragma unroll
                for (int s = 0; s < KSTEP; ++s) {
                    f32x4 dd = MFMA(FaLo, B0[s], bd);
                    dd = MFMA(FbLo, hB, dd);
                    f32x4 dh = MFMA(FaHi, B0[s], bdh);
                    dh = MFMA(FbHi, hB, dh);
                    hB = xform(dd, dh, b, g);
                    h1b[(m - 1) & 1][s][b][g] = __builtin_bit_cast(uint4, hB);
                }
            }
        } else {
            if (m >= 2) {
                f16x8 B1[KSTEP];
                #pragma unroll
                for (int s = 0; s < KSTEP; ++s)
                    B1[s] = __builtin_bit_cast(f16x8, h1b[m & 1][s][b][g]);  // (m-2)&1
                #pragma unroll
                for (int s = 0; s < KSTEP; ++s) {
                    f32x4 dd = MFMA(FaLo, B1[s], bd);
                    dd = MFMA(FbLo, hB, dd);
                    f32x4 dh = MFMA(FaHi, B1[s], bdh);
                    dh = MFMA(FbHi, hB, dh);
                    hB = xform(dd, dh, b, g);
                }
            }
        }
    }

    // ---- FC epilogue: wave2's hB = h2(511) (R14-validated reduce) ----
    if (wv == 2) {
        float acc = 0.f;
        #pragma unroll
        for (int i = 0; i < 8; ++i) {
            int k = 8 * g + i;
            if (k < H) acc = fmaf((float)hB[i], fc_w[k], acc);
        }
        acc += __shfl_xor(acc, 16);
        acc += __shfl_xor(acc, 32);
        if (l < 16) out[gb0 + l] = acc + fc_b[0];
    }
}

extern "C" void kernel_launch(void* const* d_in, const int* in_sizes, int n_in,
                              void* d_out, int out_size, void* d_ws, size_t ws_size,
                              hipStream_t stream) {
    const float* x     = (const float*)d_in[0];
    const float* w_ih0 = (const float*)d_in[1];
    const float* w_hh0 = (const float*)d_in[2];
    const float* b_ih0 = (const float*)d_in[3];
    const float* b_hh0 = (const float*)d_in[4];
    const float* w_ih1 = (const float*)d_in[5];
    const float* w_hh1 = (const float*)d_in[6];
    const float* b_ih1 = (const float*)d_in[7];
    const float* b_hh1 = (const float*)d_in[8];
    const float* w_ih2 = (const float*)d_in[9];
    const float* w_hh2 = (const float*)d_in[10];
    const float* b_ih2 = (const float*)d_in[11];
    const float* b_hh2 = (const float*)d_in[12];
    const float* fc_w  = (const float*)d_in[13];
    const float* fc_b  = (const float*)d_in[14];
    float* out = (float*)d_out;
    unsigned int* wpk = (unsigned int*)d_ws;   // 5 * 32 * 16 * 4 = 10240 B

    prep_w<<<1, 256, 0, stream>>>(w_hh0, w_ih1, w_hh1, w_ih2, w_hh2, wpk);

    rnn_mfma<<<B_TOTAL / 16, 192, 0, stream>>>(
        x, w_ih0, b_ih0, b_hh0, b_ih1, b_hh1, b_ih2, b_hh2,
        fc_w, fc_b, wpk, out);
}

// Round 16
// 183.111 us; speedup vs baseline: 1.7124x; 1.0184x over previous
//
#include <hip/hip_runtime.h>
#include <hip/hip_fp16.h>

// B=8192, T=512, IN=1, H=20, OUT=1
#define B_TOTAL 8192
#define T_LEN   512
#define H       20
#define XSTR    516          // xs row stride (floats): 516%32=4 -> 2-way max (free)
#define WROW    16           // packed weight row stride in dwords (64B)
#define KSTEP   4            // timesteps per barrier (super-tick)
// wpk layout (R13-validated): matrix m {0:whh0,1:wih1,2:whh1,3:wih2,4:whh2},
// 32 rows each (rows 20..31 zero), row r: dwords 0..9 = f16 pairs of W[r][0..19].
// A-frag lane(b,g): row b (or 16+b), dwords 4g..4g+3.

typedef _Float16 f16x8 __attribute__((ext_vector_type(8)));
typedef float    f32x4 __attribute__((ext_vector_type(4)));
typedef unsigned int u32;

#define MFMA(a, bf, c) __builtin_amdgcn_mfma_f32_16x16x32_f16((a), (bf), (c), 0, 0, 0)

__device__ __forceinline__ float fast_tanh(float x) {
    float e = __builtin_amdgcn_exp2f(x * 2.885390081777927f);
    return fmaf(-2.0f, __builtin_amdgcn_rcpf(e + 1.0f), 1.0f);
}

__device__ __forceinline__ u32 pk2(float a, float b) {
    return __builtin_bit_cast(u32, __builtin_amdgcn_cvt_pkrtz(a, b));
}

// D-layout -> B-fragment transform, in-register via ds_bpermute (R14-validated).
__device__ __forceinline__ f16x8 xform(f32x4 d, f32x4 dh, int b, int g) {
    u32 p0  = pk2(fast_tanh(d[0]),  fast_tanh(d[1]));
    u32 p1  = pk2(fast_tanh(d[2]),  fast_tanh(d[3]));
    u32 ph0 = pk2(fast_tanh(dh[0]), fast_tanh(dh[1]));
    u32 ph1 = pk2(fast_tanh(dh[2]), fast_tanh(dh[3]));
    const int gl = g & 1;
    const int a0 = (b + 32 * gl) * 4;        // src lane (b, 2g)   [g<2]
    const int a1 = (b + 16 + 32 * gl) * 4;   // src lane (b, 2g+1) [g<2]
    u32 r0 = (u32)__builtin_amdgcn_ds_bpermute(a0, (int)p0);
    u32 r1 = (u32)__builtin_amdgcn_ds_bpermute(a0, (int)p1);
    u32 r2 = (u32)__builtin_amdgcn_ds_bpermute(a1, (int)p0);
    u32 r3 = (u32)__builtin_amdgcn_ds_bpermute(a1, (int)p1);
    u32 s0 = (u32)__builtin_amdgcn_ds_bpermute(b * 4, (int)ph0);
    u32 s1 = (u32)__builtin_amdgcn_ds_bpermute(b * 4, (int)ph1);
    uint4 dw;
    dw.x = g < 2 ? r0 : (g == 2 ? s0 : 0u);
    dw.y = g < 2 ? r1 : (g == 2 ? s1 : 0u);
    dw.z = g < 2 ? r2 : 0u;
    dw.w = g < 2 ? r3 : 0u;
    return __builtin_bit_cast(f16x8, dw);
}

// ---- prologue: pack 5 HxH f32 matrices into padded f16-pair rows (R13) ----
__global__ void prep_w(const float* __restrict__ w_hh0, const float* __restrict__ w_ih1,
                       const float* __restrict__ w_hh1, const float* __restrict__ w_ih2,
                       const float* __restrict__ w_hh2, unsigned int* __restrict__ ws)
{
    int i = threadIdx.x;                 // 256 threads, first 160 = (m, r)
    if (i < 160) {
        int m = i >> 5, r = i & 31;
        const float* src = (m == 0) ? w_hh0 : (m == 1) ? w_ih1 :
                           (m == 2) ? w_hh1 : (m == 3) ? w_ih2 : w_hh2;
        unsigned int* dst = ws + (m * 32 + r) * WROW;
        #pragma unroll
        for (int q = 0; q < 10; ++q) {
            unsigned int v = 0;
            if (r < H) {
                _Float16 lo = (_Float16)src[r * H + 2 * q];
                _Float16 hi = (_Float16)src[r * H + 2 * q + 1];
                v = (unsigned int)__builtin_bit_cast(unsigned short, lo)
                  | ((unsigned int)__builtin_bit_cast(unsigned short, hi) << 16);
            }
            dst[q] = v;
        }
        #pragma unroll
        for (int q = 10; q < 16; ++q) dst[q] = 0;
    }
}

// 3 waves/block (one layer each), 16 batches/block, KSTEP=4 per barrier.
// Hoisted MFMAs: P[s]=MFMA(Fa,B_in[s],bias) has no recurrent dep -> computed at
// super-tick top; per-step serial chain = ONE MFMA + xform. Handoff buffers are
// flat per-lane (lane l <-> slot l) -> 2-way bank aliasing only (free).
__global__ __launch_bounds__(192, 2) void rnn_mfma(
    const float* __restrict__ x,
    const float* __restrict__ w_ih0,
    const float* __restrict__ b_ih0, const float* __restrict__ b_hh0,
    const float* __restrict__ b_ih1, const float* __restrict__ b_hh1,
    const float* __restrict__ b_ih2, const float* __restrict__ b_hh2,
    const float* __restrict__ fc_w,  const float* __restrict__ fc_b,
    const unsigned int* __restrict__ wpk,
    float* __restrict__ out)
{
    __shared__ __align__(16) float xs[16][XSTR];
    __shared__ __align__(16) uint4 h0b[2][KSTEP][64];   // wv0 -> wv1, slot = lane
    __shared__ __align__(16) uint4 h1b[2][KSTEP][64];   // wv1 -> wv2, slot = lane

    const int tid = threadIdx.x;
    const int wv  = tid >> 6;
    const int l   = tid & 63;
    const int b   = l & 15;
    const int g   = l >> 4;
    const int gb0 = blockIdx.x * 16;

    // ---- stage x (coalesced float4) ----
    for (int i = tid; i < 16 * 128; i += 192) {
        int row = i >> 7, col = (i & 127) * 4;
        *(float4*)&xs[row][col] = *(const float4*)(x + (size_t)(gb0 + row) * T_LEN + col);
    }

    // ---- per-wave weight A-fragments ----
    const int mA = (wv == 0) ? 0 : (wv == 1) ? 1 : 3;
    const int mB = (wv == 0) ? 0 : (wv == 1) ? 2 : 4;
    const f16x8* wp = (const f16x8*)wpk;
    const f16x8 FaLo = wp[(mA * 32 +      b) * 4 + g];
    const f16x8 FaHi = wp[(mA * 32 + 16 + b) * 4 + g];
    const f16x8 FbLo = wp[(mB * 32 +      b) * 4 + g];
    const f16x8 FbHi = wp[(mB * 32 + 16 + b) * 4 + g];

    // ---- per-wave biases (D layout) + w_ih0 column for wave 0 ----
    const float* bi = (wv == 0) ? b_ih0 : (wv == 1) ? b_ih1 : b_ih2;
    const float* bh = (wv == 0) ? b_hh0 : (wv == 1) ? b_hh1 : b_hh2;
    f32x4 bd, bdh, w0d, w0h;
    #pragma unroll
    for (int r = 0; r < 4; ++r) {
        int j = 4 * g + r;
        bd[r]  = bi[j] + bh[j];
        bdh[r] = bi[16 + r] + bh[16 + r];
        w0d[r] = w_ih0[j];
        w0h[r] = w_ih0[16 + r];
    }

    // ---- own-layer recurrent state, B-fragment layout, in registers ----
    uint4 z; z.x = 0u; z.y = 0u; z.z = 0u; z.w = 0u;
    f16x8 hB = __builtin_bit_cast(f16x8, z);

    const int NSUP = T_LEN / KSTEP + 2;   // 130 super-ticks

    for (int m = 0; m < NSUP; ++m) {
        __syncthreads();
        if (wv == 0) {
            if (m < T_LEN / KSTEP) {
                // P[s] = x-injection + bias (no recurrent dep)
                f32x4 P[KSTEP], Ph[KSTEP];
                #pragma unroll
                for (int s = 0; s < KSTEP; ++s) {
                    float xv = xs[b][KSTEP * m + s];
                    #pragma unroll
                    for (int r = 0; r < 4; ++r) {
                        P[s][r]  = fmaf(xv, w0d[r], bd[r]);
                        Ph[s][r] = fmaf(xv, w0h[r], bdh[r]);
                    }
                }
                #pragma unroll
                for (int s = 0; s < KSTEP; ++s) {
                    f32x4 dd = MFMA(FaLo, hB, P[s]);
                    f32x4 dh = MFMA(FaHi, hB, Ph[s]);
                    hB = xform(dd, dh, b, g);
                    h0b[m & 1][s][l] = __builtin_bit_cast(uint4, hB);
                }
            }
        } else if (wv == 1) {
            if (m >= 1 && m <= T_LEN / KSTEP) {
                // Hoist: P[s] = MFMA(FaLo, B0[s], bd) — independent of hB.
                f32x4 P[KSTEP], Ph[KSTEP];
                #pragma unroll
                for (int s = 0; s < KSTEP; ++s) {
                    f16x8 B0 = __builtin_bit_cast(f16x8, h0b[(m - 1) & 1][s][l]);
                    P[s]  = MFMA(FaLo, B0, bd);
                    Ph[s] = MFMA(FaHi, B0, bdh);
                }
                #pragma unroll
                for (int s = 0; s < KSTEP; ++s) {
                    f32x4 dd = MFMA(FbLo, hB, P[s]);
                    f32x4 dh = MFMA(FbHi, hB, Ph[s]);
                    hB = xform(dd, dh, b, g);
                    h1b[(m - 1) & 1][s][l] = __builtin_bit_cast(uint4, hB);
                }
            }
        } else {
            if (m >= 2) {
                f32x4 P[KSTEP], Ph[KSTEP];
                #pragma unroll
                for (int s = 0; s < KSTEP; ++s) {
                    f16x8 B1 = __builtin_bit_cast(f16x8, h1b[m & 1][s][l]);  // (m-2)&1
                    P[s]  = MFMA(FaLo, B1, bd);
                    Ph[s] = MFMA(FaHi, B1, bdh);
                }
                #pragma unroll
                for (int s = 0; s < KSTEP; ++s) {
                    f32x4 dd = MFMA(FbLo, hB, P[s]);
                    f32x4 dh = MFMA(FbHi, hB, Ph[s]);
                    hB = xform(dd, dh, b, g);
                }
            }
        }
    }

    // ---- FC epilogue: wave2's hB = h2(511) (R14-validated reduce) ----
    if (wv == 2) {
        float acc = 0.f;
        #pragma unroll
        for (int i = 0; i < 8; ++i) {
            int k = 8 * g + i;
            if (k < H) acc = fmaf((float)hB[i], fc_w[k], acc);
        }
        acc += __shfl_xor(acc, 16);
        acc += __shfl_xor(acc, 32);
        if (l < 16) out[gb0 + l] = acc + fc_b[0];
    }
}

extern "C" void kernel_launch(void* const* d_in, const int* in_sizes, int n_in,
                              void* d_out, int out_size, void* d_ws, size_t ws_size,
                              hipStream_t stream) {
    const float* x     = (const float*)d_in[0];
    const float* w_ih0 = (const float*)d_in[1];
    const float* w_hh0 = (const float*)d_in[2];
    const float* b_ih0 = (const float*)d_in[3];
    const float* b_hh0 = (const float*)d_in[4];
    const float* w_ih1 = (const float*)d_in[5];
    const float* w_hh1 = (const float*)d_in[6];
    const float* b_ih1 = (const float*)d_in[7];
    const float* b_hh1 = (const float*)d_in[8];
    const float* w_ih2 = (const float*)d_in[9];
    const float* w_hh2 = (const float*)d_in[10];
    const float* b_ih2 = (const float*)d_in[11];
    const float* b_hh2 = (const float*)d_in[12];
    const float* fc_w  = (const float*)d_in[13];
    const float* fc_b  = (const float*)d_in[14];
    float* out = (float*)d_out;
    unsigned int* wpk = (unsigned int*)d_ws;   // 5 * 32 * 16 * 4 = 10240 B

    prep_w<<<1, 256, 0, stream>>>(w_hh0, w_ih1, w_hh1, w_ih2, w_hh2, wpk);

    rnn_mfma<<<B_TOTAL / 16, 192, 0, stream>>>(
        x, w_ih0, b_ih0, b_hh0, b_ih1, b_hh1, b_ih2, b_hh2,
        fc_w, fc_b, wpk, out);
}

// Round 18
// 161.825 us; speedup vs baseline: 1.9377x; 1.1315x over previous
//
#include <hip/hip_runtime.h>
#include <hip/hip_fp16.h>

// B=8192, T=512, IN=1, H=20, OUT=1
#define B_TOTAL 8192
#define T_LEN   512
#define H       20
#define XSTR    516            // xs row stride (floats): 2-way bank alias max (free)
#define KSTEP   4              // timesteps per barrier
#define NSUPER  (T_LEN / KSTEP)

typedef _Float16 f16x4 __attribute__((ext_vector_type(4)));
typedef float    f32x4 __attribute__((ext_vector_type(4)));
typedef unsigned int u32;

// 16x16x16 f16 MFMA: A/B = 2 VGPRs (f16x4), C/D = 4 VGPRs. Key property:
// D lane(b,g) rows j=4g+r ; B lane(b,g) k=4g+i -> SAME lane/granularity, so
// tanh(D)+pack feeds the next step with ZERO cross-lane operations.
// NOTE: __has_builtin is FALSE in the HOST pass -> gate on __HIP_DEVICE_COMPILE__
// and give the host a parse-only stub (host never executes device code).
#if defined(__HIP_DEVICE_COMPILE__)
  #if __has_builtin(__builtin_amdgcn_mfma_f32_16x16x16_f16)
    #define MFMA16(a, b, c) __builtin_amdgcn_mfma_f32_16x16x16_f16((a), (b), (c), 0, 0, 0)
  #elif __has_builtin(__builtin_amdgcn_mfma_f32_16x16x16f16)
    #define MFMA16(a, b, c) __builtin_amdgcn_mfma_f32_16x16x16f16((a), (b), (c), 0, 0, 0)
  #else
    #error "no 16x16x16 f16 MFMA builtin on device"
  #endif
#else
  #define MFMA16(a, b, c) (c)   // host parse stub
#endif

__device__ __forceinline__ float fast_tanh(float x) {
    float e = __builtin_amdgcn_exp2f(x * 2.885390081777927f);
    return fmaf(-2.0f, __builtin_amdgcn_rcpf(e + 1.0f), 1.0f);
}
__device__ __forceinline__ u32 pk2(float a, float b) {
    return __builtin_bit_cast(u32, __builtin_amdgcn_cvt_pkrtz(a, b));
}
__device__ __forceinline__ f16x4 u2f(uint2 v) { return __builtin_bit_cast(f16x4, v); }

// ---- prologue: pack 5 HxH matrices into 16x16x16 A-fragments ----
// Entry e = (m, f, l): m = matrix {0:whh0,1:wih1,2:whh1,3:wih2,4:whh2},
// f = frag {0: j0-15/k0-15, 1: j0-15/k16-31, 2: j16-31/k0-15, 3: j16-31/k16-31},
// lane l=(p,g): row = (f&2 ? 16+p : p), k = (f&1 ? 16:0) + 4g + i. OOB -> 0.
__global__ void prep_w(const float* __restrict__ w_hh0, const float* __restrict__ w_ih1,
                       const float* __restrict__ w_hh1, const float* __restrict__ w_ih2,
                       const float* __restrict__ w_hh2, u32* __restrict__ ws)
{
    for (int e = threadIdx.x; e < 5 * 4 * 64; e += 256) {
        int l = e & 63, f = (e >> 6) & 3, m = e >> 8;
        const float* src = (m == 0) ? w_hh0 : (m == 1) ? w_ih1 :
                           (m == 2) ? w_hh1 : (m == 3) ? w_ih2 : w_hh2;
        int p = l & 15, g = l >> 4;
        int row = (f & 2) ? 16 + p : p;
        int kb  = ((f & 1) ? 16 : 0) + 4 * g;
        u32 d0 = 0, d1 = 0;
        if (row < H) {
            unsigned short h[4];
            #pragma unroll
            for (int i = 0; i < 4; ++i) {
                int k = kb + i;
                _Float16 v = (k < H) ? (_Float16)src[row * H + k] : (_Float16)0.f;
                h[i] = __builtin_bit_cast(unsigned short, v);
            }
            d0 = (u32)h[0] | ((u32)h[1] << 16);
            d1 = (u32)h[2] | ((u32)h[3] << 16);
        }
        ws[e * 2 + 0] = d0;
        ws[e * 2 + 1] = d1;
    }
}

// 3 waves/block (one layer each), 16 batches/block, KSTEP=4 per barrier.
// Recurrent state lives in 4 dwords/lane (Hlo k=4g..4g+3, Hhi k=16..19 on g==0);
// per-step chain = 2 chained MFMAs + 4 tanh + 2 pack. No bpermute anywhere.
__global__ __launch_bounds__(192, 2) void rnn_mfma(
    const float* __restrict__ x,
    const float* __restrict__ w_ih0,
    const float* __restrict__ b_ih0, const float* __restrict__ b_hh0,
    const float* __restrict__ b_ih1, const float* __restrict__ b_hh1,
    const float* __restrict__ b_ih2, const float* __restrict__ b_hh2,
    const float* __restrict__ fc_w,  const float* __restrict__ fc_b,
    const u32* __restrict__ wpk,
    float* __restrict__ out)
{
    __shared__ __align__(16) float xs[16][XSTR];
    __shared__ __align__(16) uint4 h0b[2][KSTEP][64];   // wv0 -> wv1, slot = lane
    __shared__ __align__(16) uint4 h1b[2][KSTEP][64];   // wv1 -> wv2, slot = lane

    const int tid = threadIdx.x;
    const int wv  = tid >> 6;
    const int l   = tid & 63;
    const int b   = l & 15;
    const int g   = l >> 4;
    const int gb0 = blockIdx.x * 16;

    // ---- stage x (coalesced float4) ----
    for (int i = tid; i < 16 * 128; i += 192) {
        int row = i >> 7, col = (i & 127) * 4;
        *(float4*)&xs[row][col] = *(const float4*)(x + (size_t)(gb0 + row) * T_LEN + col);
    }

    // ---- weight A-fragments (2 dwords each) ----
    const int mA = (wv == 1) ? 1 : 3;                       // input matrix (wv1/wv2)
    const int mB = (wv == 0) ? 0 : (wv == 1) ? 2 : 4;       // recurrent matrix
    f16x4 IAlo1 = {}, IAhi1 = {}, IAlo2 = {}, IAhi2 = {};
    if (wv != 0) {
        IAlo1 = u2f(*(const uint2*)(wpk + ((mA * 4 + 0) * 64 + l) * 2));
        IAhi1 = u2f(*(const uint2*)(wpk + ((mA * 4 + 1) * 64 + l) * 2));
        IAlo2 = u2f(*(const uint2*)(wpk + ((mA * 4 + 2) * 64 + l) * 2));
        IAhi2 = u2f(*(const uint2*)(wpk + ((mA * 4 + 3) * 64 + l) * 2));
    }
    const f16x4 RAlo1 = u2f(*(const uint2*)(wpk + ((mB * 4 + 0) * 64 + l) * 2));
    const f16x4 RAhi1 = u2f(*(const uint2*)(wpk + ((mB * 4 + 1) * 64 + l) * 2));
    const f16x4 RAlo2 = u2f(*(const uint2*)(wpk + ((mB * 4 + 2) * 64 + l) * 2));
    const f16x4 RAhi2 = u2f(*(const uint2*)(wpk + ((mB * 4 + 3) * 64 + l) * 2));

    // ---- biases in D layout (tile1: j=4g+r; tile2: j=16+r on g==0) ----
    const float* bi = (wv == 0) ? b_ih0 : (wv == 1) ? b_ih1 : b_ih2;
    const float* bh = (wv == 0) ? b_hh0 : (wv == 1) ? b_hh1 : b_hh2;
    f32x4 bd1, bd2, w0lo, w0hi;
    #pragma unroll
    for (int r = 0; r < 4; ++r) {
        int j = 4 * g + r;
        bd1[r]  = bi[j] + bh[j];
        bd2[r]  = (g == 0) ? bi[16 + r] + bh[16 + r] : 0.f;
        w0lo[r] = w_ih0[j];
        w0hi[r] = (g == 0) ? w_ih0[16 + r] : 0.f;
    }

    // ---- recurrent state: Hlo = h[4g..4g+3], Hhi = h[16..19] (g==0), else 0 ----
    f16x4 Hlo = {}, Hhi = {};

    for (int m = 0; m < NSUPER + 2; ++m) {
        __syncthreads();
        if (wv == 0) {
            if (m < NSUPER) {
                f32x4 P1[KSTEP], P2[KSTEP];
                #pragma unroll
                for (int s = 0; s < KSTEP; ++s) {
                    float xv = xs[b][KSTEP * m + s];
                    #pragma unroll
                    for (int r = 0; r < 4; ++r) {
                        P1[s][r] = fmaf(xv, w0lo[r], bd1[r]);
                        P2[s][r] = fmaf(xv, w0hi[r], bd2[r]);
                    }
                }
                #pragma unroll
                for (int s = 0; s < KSTEP; ++s) {
                    f32x4 D1 = MFMA16(RAlo1, Hlo, P1[s]); D1 = MFMA16(RAhi1, Hhi, D1);
                    f32x4 D2 = MFMA16(RAlo2, Hlo, P2[s]); D2 = MFMA16(RAhi2, Hhi, D2);
                    u32 a0 = pk2(fast_tanh(D1[0]), fast_tanh(D1[1]));
                    u32 a1 = pk2(fast_tanh(D1[2]), fast_tanh(D1[3]));
                    u32 a2 = pk2(fast_tanh(D2[0]), fast_tanh(D2[1]));
                    u32 a3 = pk2(fast_tanh(D2[2]), fast_tanh(D2[3]));
                    Hlo = u2f(make_uint2(a0, a1));
                    Hhi = u2f(make_uint2(a2, a3));
                    h0b[m & 1][s][l] = make_uint4(a0, a1, a2, a3);
                }
            }
        } else if (wv == 1) {
            if (m >= 1 && m <= NSUPER) {
                f32x4 P1[KSTEP], P2[KSTEP];
                #pragma unroll
                for (int s = 0; s < KSTEP; ++s) {
                    uint4 v = h0b[(m - 1) & 1][s][l];
                    f16x4 Blo = u2f(make_uint2(v.x, v.y));
                    f16x4 Bhi = u2f(make_uint2(v.z, v.w));
                    P1[s] = MFMA16(IAlo1, Blo, bd1); P1[s] = MFMA16(IAhi1, Bhi, P1[s]);
                    P2[s] = MFMA16(IAlo2, Blo, bd2); P2[s] = MFMA16(IAhi2, Bhi, P2[s]);
                }
                #pragma unroll
                for (int s = 0; s < KSTEP; ++s) {
                    f32x4 D1 = MFMA16(RAlo1, Hlo, P1[s]); D1 = MFMA16(RAhi1, Hhi, D1);
                    f32x4 D2 = MFMA16(RAlo2, Hlo, P2[s]); D2 = MFMA16(RAhi2, Hhi, D2);
                    u32 a0 = pk2(fast_tanh(D1[0]), fast_tanh(D1[1]));
                    u32 a1 = pk2(fast_tanh(D1[2]), fast_tanh(D1[3]));
                    u32 a2 = pk2(fast_tanh(D2[0]), fast_tanh(D2[1]));
                    u32 a3 = pk2(fast_tanh(D2[2]), fast_tanh(D2[3]));
                    Hlo = u2f(make_uint2(a0, a1));
                    Hhi = u2f(make_uint2(a2, a3));
                    h1b[(m - 1) & 1][s][l] = make_uint4(a0, a1, a2, a3);
                }
            }
        } else {
            if (m >= 2) {
                f32x4 P1[KSTEP], P2[KSTEP];
                #pragma unroll
                for (int s = 0; s < KSTEP; ++s) {
                    uint4 v = h1b[m & 1][s][l];          // (m-2)&1 == m&1
                    f16x4 Blo = u2f(make_uint2(v.x, v.y));
                    f16x4 Bhi = u2f(make_uint2(v.z, v.w));
                    P1[s] = MFMA16(IAlo1, Blo, bd1); P1[s] = MFMA16(IAhi1, Bhi, P1[s]);
                    P2[s] = MFMA16(IAlo2, Blo, bd2); P2[s] = MFMA16(IAhi2, Bhi, P2[s]);
                }
                #pragma unroll
                for (int s = 0; s < KSTEP; ++s) {
                    f32x4 D1 = MFMA16(RAlo1, Hlo, P1[s]); D1 = MFMA16(RAhi1, Hhi, D1);
                    f32x4 D2 = MFMA16(RAlo2, Hlo, P2[s]); D2 = MFMA16(RAhi2, Hhi, D2);
                    u32 a0 = pk2(fast_tanh(D1[0]), fast_tanh(D1[1]));
                    u32 a1 = pk2(fast_tanh(D1[2]), fast_tanh(D1[3]));
                    u32 a2 = pk2(fast_tanh(D2[0]), fast_tanh(D2[1]));
                    u32 a3 = pk2(fast_tanh(D2[2]), fast_tanh(D2[3]));
                    Hlo = u2f(make_uint2(a0, a1));
                    Hhi = u2f(make_uint2(a2, a3));
                }
            }
        }
    }

    // ---- FC epilogue: wave2 holds h2(511) in Hlo/Hhi ----
    if (wv == 2) {
        float acc = 0.f;
        #pragma unroll
        for (int i = 0; i < 4; ++i)
            acc = fmaf((float)Hlo[i], fc_w[4 * g + i], acc);
        if (g == 0) {
            #pragma unroll
            for (int i = 0; i < 4; ++i)
                acc = fmaf((float)Hhi[i], fc_w[16 + i], acc);
        }
        acc += __shfl_xor(acc, 16);
        acc += __shfl_xor(acc, 32);
        if (l < 16) out[gb0 + l] = acc + fc_b[0];
    }
}

extern "C" void kernel_launch(void* const* d_in, const int* in_sizes, int n_in,
                              void* d_out, int out_size, void* d_ws, size_t ws_size,
                              hipStream_t stream) {
    const float* x     = (const float*)d_in[0];
    const float* w_ih0 = (const float*)d_in[1];
    const float* w_hh0 = (const float*)d_in[2];
    const float* b_ih0 = (const float*)d_in[3];
    const float* b_hh0 = (const float*)d_in[4];
    const float* w_ih1 = (const float*)d_in[5];
    const float* w_hh1 = (const float*)d_in[6];
    const float* b_ih1 = (const float*)d_in[7];
    const float* b_hh1 = (const float*)d_in[8];
    const float* w_ih2 = (const float*)d_in[9];
    const float* w_hh2 = (const float*)d_in[10];
    const float* b_ih2 = (const float*)d_in[11];
    const float* b_hh2 = (const float*)d_in[12];
    const float* fc_w  = (const float*)d_in[13];
    const float* fc_b  = (const float*)d_in[14];
    float* out = (float*)d_out;
    u32* wpk = (u32*)d_ws;   // 5 * 4 * 64 * 2 * 4 = 10240 B

    prep_w<<<1, 256, 0, stream>>>(w_hh0, w_ih1, w_hh1, w_ih2, w_hh2, wpk);

    rnn_mfma<<<B_TOTAL / 16, 192, 0, stream>>>(
        x, w_ih0, b_ih0, b_hh0, b_ih1, b_hh1, b_ih2, b_hh2,
        fc_w, fc_b, wpk, out);
}